// Round 1
// baseline (1494.759 us; speedup 1.0000x reference)
//
#include <hip/hip_runtime.h>

// HMM scaled forward algorithm.
//   BATCH=128, T=8192, N_STATES=128, EMIT=64
// Strategy:
//   1) decode_onehot: stream 256 MiB one-hot -> 1 MiB uint8 obs[b][t]  (HBM-bound)
//   2) hmm_scan: chunk time axis into 8 chunks of 1024 per batch, each chunk
//      runs W=32 warmup steps from uniform alpha (mixing makes state exact to
//      fp32 precision), then accumulates its partial sum of log Z_t.
//      1024 workgroups, 256 threads each. A held in registers (64 VGPR/thread
//      = one half-column), alpha broadcast from LDS, B in LDS.
//   3) combine_ll: loglik[b] = sum of 8 chunk partials.

#define BATCH 128
#define TLEN 8192
#define NS 128
#define EMIT 64
#define NCHUNK 8
#define CLEN (TLEN / NCHUNK)   // 1024
#define WARM 32

__global__ __launch_bounds__(256) void decode_onehot(
        const float4* __restrict__ x, unsigned char* __restrict__ obs) {
    int i = blockIdx.x * blockDim.x + threadIdx.x;  // over BATCH*TLEN*16 float4s
    float4 v = x[i];
    int e = -1;
    if (v.x > 0.5f) e = 0;
    else if (v.y > 0.5f) e = 1;
    else if (v.z > 0.5f) e = 2;
    else if (v.w > 0.5f) e = 3;
    if (e >= 0) {
        int elem = (i << 2) | e;
        obs[elem >> 6] = (unsigned char)(elem & 63);
    }
}

__global__ __launch_bounds__(256, 4) void hmm_scan(
        const float* __restrict__ Ivec,
        const float* __restrict__ Amat,
        const float* __restrict__ Bmat,
        const unsigned char* __restrict__ obs,
        float* __restrict__ out_alpha,   // [BATCH][NS]
        float* __restrict__ pll)         // [BATCH][NCHUNK]
{
    __shared__ __align__(16) float Bl[EMIT * NS];   // 32 KB emission table
    __shared__ __align__(16) float alpha[NS];       // normalized forward state
    __shared__ float part[2 * NS];                  // matvec partials
    __shared__ float red[2];                        // per-wave Z partials
    __shared__ unsigned char obs_l[WARM + CLEN];

    const int tid = threadIdx.x;
    const int b = blockIdx.x >> 3;        // / NCHUNK
    const int c = blockIdx.x & (NCHUNK - 1);
    const int s = tid & (NS - 1);
    const int h = tid >> 7;               // which k-half this thread owns

    // stage B into LDS (coalesced float4)
    {
        const float4* Bg = (const float4*)Bmat;
        float4* Bd = (float4*)Bl;
        for (int i = tid; i < EMIT * NS / 4; i += 256) Bd[i] = Bg[i];
    }

    const bool first = (c == 0);
    const int t_begin = first ? 0 : (c * CLEN - WARM);
    const int n_iter = first ? CLEN : (WARM + CLEN);

    // stage this chunk's obs bytes
    for (int i = tid; i < n_iter; i += 256)
        obs_l[i] = obs[b * TLEN + t_begin + i];

    // A half-column in registers: A_reg[j] = A[h*64+j][s]
    float A_reg[64];
    #pragma unroll
    for (int j = 0; j < 64; ++j)
        A_reg[j] = Amat[(h * 64 + j) * NS + s];

    if (!first && tid < NS) alpha[tid] = 1.0f / NS;   // uniform warmup init
    __syncthreads();

    float ll = 0.0f;
    float last_a = 0.0f;
    const bool have_r = (tid < NS);

    for (int it = 0; it < n_iter; ++it) {
        float r = 0.0f;
        if (first && it == 0) {
            // t==0 exact init: alpha0 = E0 * I  (R := I, no A-multiply)
            if (have_r) r = Ivec[s];
        } else {
            // R[s] = sum_k alpha_hat[k] * A[k][s], split across 2 k-halves
            float a0 = 0.f, a1 = 0.f, a2 = 0.f, a3 = 0.f;
            const float4* al = (const float4*)(alpha + h * 64);
            #pragma unroll
            for (int j4 = 0; j4 < 16; ++j4) {
                float4 a4 = al[j4];          // broadcast read (uniform addr)
                a0 += a4.x * A_reg[4 * j4 + 0];
                a1 += a4.y * A_reg[4 * j4 + 1];
                a2 += a4.z * A_reg[4 * j4 + 2];
                a3 += a4.w * A_reg[4 * j4 + 3];
            }
            part[tid] = (a0 + a1) + (a2 + a3);
            __syncthreads();
            if (have_r) r = part[s] + part[NS + s];
        }

        float a_new = 0.0f;
        if (have_r) {
            int o = obs_l[it];
            a_new = Bl[o * NS + s] * r;      // E * R
            float zz = a_new;                // wave-reduce Z over 64 lanes
            #pragma unroll
            for (int off = 32; off >= 1; off >>= 1)
                zz += __shfl_down(zz, off, 64);
            if ((tid & 63) == 0) red[tid >> 6] = zz;
        }
        __syncthreads();
        if (have_r) {
            float Z = red[0] + red[1];
            alpha[s] = a_new / Z;            // renormalize
            if (first || it >= WARM) ll += logf(Z);
            last_a = a_new;                  // pre-normalization alpha_t
        }
        __syncthreads();
    }

    if (c == NCHUNK - 1 && tid < NS)
        out_alpha[b * NS + s] = last_a;      // alpha_f (unnormalized, as ref)
    if (tid == 0)
        pll[b * NCHUNK + c] = ll;
}

__global__ void combine_ll(const float* __restrict__ pll,
                           float* __restrict__ out_ll) {
    int b = threadIdx.x;
    float sum = 0.f;
    #pragma unroll
    for (int cc = 0; cc < NCHUNK; ++cc) sum += pll[b * NCHUNK + cc];
    out_ll[b] = sum;
}

extern "C" void kernel_launch(void* const* d_in, const int* in_sizes, int n_in,
                              void* d_out, int out_size, void* d_ws, size_t ws_size,
                              hipStream_t stream) {
    const float* x = (const float*)d_in[0];   // [B, T, EMIT] one-hot fp32
    const float* I = (const float*)d_in[1];   // [NS]
    const float* A = (const float*)d_in[2];   // [NS, NS]
    const float* B = (const float*)d_in[3];   // [EMIT, NS]
    float* out = (float*)d_out;               // alpha_f [B*NS] ++ loglik [B]

    unsigned char* obs = (unsigned char*)d_ws;                 // 1 MiB
    float* pll = (float*)((char*)d_ws + BATCH * TLEN);         // 4 KiB

    decode_onehot<<<(BATCH * TLEN * 16) / 256, 256, 0, stream>>>(
        (const float4*)x, obs);
    hmm_scan<<<BATCH * NCHUNK, 256, 0, stream>>>(I, A, B, obs, out, pll);
    combine_ll<<<1, BATCH, 0, stream>>>(pll, out + BATCH * NS);
}

// Round 2
// 487.425 us; speedup vs baseline: 3.0666x; 3.0666x over previous
//
#include <hip/hip_runtime.h>

// HMM scaled forward, MFMA version.
//   BATCH=128, T=8192, N_STATES=128, EMIT=64
// 1) decode_onehot: 256 MiB one-hot -> obsG[bg][t][16] bytes (1 MiB)
// 2) zero_ll: zero the loglik region of d_out (re-poisoned each launch)
// 3) hmm_scan: one wave per (batch-group of 16, time-chunk of 32+32 warmup).
//    Per step: 32x mfma_f32_16x16x32_bf16 computes R^T = A^T @ alpha^T
//    (A^T static in 128 VGPRs), emission via bf16 B-table in LDS,
//    Z-reduce intra-wave (shfl_xor), normalized bf16 alpha^T round-trips
//    through a 272B-stride LDS buffer (b128-aligned, bank-uniform reads).
//    loglik partials accumulate via atomicAdd (order-independent to ~1e-4).

#define BATCH 128
#define TLEN 8192
#define NS 128
#define EMIT 64
#define NCHUNK 256
#define CLEN (TLEN / NCHUNK)   // 32
#define WARM 32
#define BG 8                   // batch groups of 16
#define ASTRIDE 136            // alphaT row stride, bf16 elems (272 B, 16B-aligned reads)
#define BSTR 132               // B-table row stride, bf16 elems (264 B, 8B-aligned reads)

typedef __attribute__((ext_vector_type(8))) short short8;
typedef __attribute__((ext_vector_type(4))) float floatx4;
typedef __attribute__((ext_vector_type(4))) unsigned int uintx4;

__device__ __forceinline__ unsigned f2bf(float f) {
    return (__float_as_uint(f) + 0x8000u) >> 16;   // round-half-up to bf16
}

__global__ __launch_bounds__(256) void decode_onehot(
        const float4* __restrict__ x, unsigned char* __restrict__ obsG) {
    int i = blockIdx.x * 256 + threadIdx.x;   // BATCH*TLEN*16 float4s
    float4 v = x[i];
    float s = v.x + v.y + v.z + v.w;
    if (s > 0.5f) {
        int e = (v.y > 0.5f) ? 1 : (v.z > 0.5f) ? 2 : (v.w > 0.5f) ? 3 : 0;
        int elem = (i << 2) + e;
        int row = elem >> 6;              // b*TLEN + t
        int col = elem & 63;              // emission symbol
        int b = row >> 13;                // row / TLEN
        int t = row & (TLEN - 1);
        obsG[(b >> 4) * (TLEN * 16) + t * 16 + (b & 15)] = (unsigned char)col;
    }
}

__global__ void zero_ll(float* __restrict__ out_ll) {
    out_ll[threadIdx.x] = 0.f;
}

__global__ __launch_bounds__(64) void hmm_scan(
        const float* __restrict__ Amat,
        const float* __restrict__ Bmat,
        const float* __restrict__ Ivec,
        const unsigned char* __restrict__ obsG,
        float* __restrict__ out_alpha,    // [BATCH][NS]
        float* __restrict__ out_ll)       // [BATCH]
{
    __shared__ unsigned short Bl[EMIT * BSTR];        // 16896 B bf16 emission table
    __shared__ unsigned short aT[16 * ASTRIDE];       // 4352 B normalized alpha^T (bf16)
    __shared__ unsigned char obs_l[(CLEN + WARM) * 16];

    const int lane = threadIdx.x;
    const int n = lane & 15;              // batch within group
    const int q = lane >> 4;              // quad
    const int bg = blockIdx.x >> 8;       // / NCHUNK
    const int c = blockIdx.x & (NCHUNK - 1);
    const bool first = (c == 0);
    const int steps = first ? CLEN : (CLEN + WARM);
    const int t0 = first ? 0 : c * CLEN - WARM;

    // stage B (fp32 global -> bf16 LDS, padded stride)
    for (int i = lane; i < EMIT * NS; i += 64) {
        int e = i >> 7, col = i & (NS - 1);
        Bl[e * BSTR + col] = (unsigned short)f2bf(Bmat[i]);
    }
    // stage obs bytes for this chunk
    {
        const unsigned* src = (const unsigned*)(obsG + bg * (TLEN * 16) + t0 * 16);
        unsigned* dst = (unsigned*)obs_l;
        for (int i = lane; i < steps * 4; i += 64) dst[i] = src[i];
    }
    // warmup init: uniform alpha (bf16(1/128) = 0x3C00)
    if (!first) {
        unsigned* dst = (unsigned*)aT;
        for (int i = lane; i < 16 * ASTRIDE / 2; i += 64) dst[i] = 0x3C003C00u;
    }
    // A^T fragments in registers: af[mt][kf] lane layout A_op[m=lane&15][k=8q+j]
    // A_op[m][k] = A[k][m]  (transition k->m)
    short8 af[8][4];
    #pragma unroll
    for (int mt = 0; mt < 8; ++mt)
        #pragma unroll
        for (int kf = 0; kf < 4; ++kf) {
            short8 v;
            #pragma unroll
            for (int j = 0; j < 8; ++j)
                v[j] = (short)f2bf(Amat[(32 * kf + 8 * q + j) * NS + 16 * mt + n]);
            af[mt][kf] = v;
        }
    __syncthreads();

    float ll = 0.f;
    const int wcut = first ? 0 : WARM;

    for (int it = 0; it < steps; ++it) {
        floatx4 acc[8];
        if (first && it == 0) {
            // t==0 exact init: R = I (broadcast per state, same for all batches)
            #pragma unroll
            for (int mt = 0; mt < 8; ++mt)
                acc[mt] = *(const floatx4*)(Ivec + 16 * mt + 4 * q);
        } else {
            short8 bf[4];
            #pragma unroll
            for (int kf = 0; kf < 4; ++kf) {
                uintx4 u = *(const uintx4*)(aT + n * ASTRIDE + 32 * kf + 8 * q);
                bf[kf] = __builtin_bit_cast(short8, u);
            }
            #pragma unroll
            for (int mt = 0; mt < 8; ++mt) {
                floatx4 a = {0.f, 0.f, 0.f, 0.f};
                #pragma unroll
                for (int kf = 0; kf < 4; ++kf)
                    a = __builtin_amdgcn_mfma_f32_16x16x32_bf16(af[mt][kf], bf[kf], a, 0, 0, 0);
                acc[mt] = a;
            }
        }

        int o = obs_l[it * 16 + n];
        float z = 0.f;
        #pragma unroll
        for (int mt = 0; mt < 8; ++mt) {
            const unsigned* ep = (const unsigned*)(Bl + o * BSTR + 16 * mt + 4 * q);
            unsigned d0 = ep[0], d1 = ep[1];
            acc[mt].x *= __uint_as_float(d0 << 16);
            acc[mt].y *= __uint_as_float(d0 & 0xFFFF0000u);
            acc[mt].z *= __uint_as_float(d1 << 16);
            acc[mt].w *= __uint_as_float(d1 & 0xFFFF0000u);
            z += (acc[mt].x + acc[mt].y) + (acc[mt].z + acc[mt].w);
        }
        z += __shfl_xor(z, 16, 64);
        z += __shfl_xor(z, 32, 64);     // Z per batch, in all 4 q-lanes

        if (it >= wcut) ll += __logf(z);

        if (c == NCHUNK - 1 && it == steps - 1) {
            // final alpha (pre-normalization), lane (q,n) holds states 16mt+4q..+3
            #pragma unroll
            for (int mt = 0; mt < 8; ++mt)
                *(floatx4*)(out_alpha + (bg * 16 + n) * NS + 16 * mt + 4 * q) = acc[mt];
        }

        float rz = __builtin_amdgcn_rcpf(z);
        #pragma unroll
        for (int mt = 0; mt < 8; ++mt) {
            unsigned u0 = __float_as_uint(acc[mt].x * rz) + 0x8000u;
            unsigned u1 = __float_as_uint(acc[mt].y * rz) + 0x8000u;
            unsigned u2 = __float_as_uint(acc[mt].z * rz) + 0x8000u;
            unsigned u3 = __float_as_uint(acc[mt].w * rz) + 0x8000u;
            unsigned lo = (u0 >> 16) | (u1 & 0xFFFF0000u);
            unsigned hi = (u2 >> 16) | (u3 & 0xFFFF0000u);
            unsigned* wp = (unsigned*)(aT + n * ASTRIDE + 16 * mt + 4 * q);
            wp[0] = lo; wp[1] = hi;
        }
        __syncthreads();   // single-wave WG: compiles to waitcnt, orders aT RAW
    }

    if (q == 0) atomicAdd(&out_ll[bg * 16 + n], ll);
}

extern "C" void kernel_launch(void* const* d_in, const int* in_sizes, int n_in,
                              void* d_out, int out_size, void* d_ws, size_t ws_size,
                              hipStream_t stream) {
    const float* x = (const float*)d_in[0];   // [B, T, EMIT] one-hot fp32
    const float* I = (const float*)d_in[1];   // [NS]
    const float* A = (const float*)d_in[2];   // [NS, NS]
    const float* B = (const float*)d_in[3];   // [EMIT, NS]
    float* out = (float*)d_out;               // alpha_f [B*NS] ++ loglik [B]

    unsigned char* obsG = (unsigned char*)d_ws;   // [BG][TLEN][16] bytes = 1 MiB

    decode_onehot<<<(BATCH * TLEN * 16) / 256, 256, 0, stream>>>(
        (const float4*)x, obsG);
    zero_ll<<<1, BATCH, 0, stream>>>(out + BATCH * NS);
    hmm_scan<<<BG * NCHUNK, 64, 0, stream>>>(A, B, I, obsG, out, out + BATCH * NS);
}

// Round 3
// 444.492 us; speedup vs baseline: 3.3628x; 1.0966x over previous
//
#include <hip/hip_runtime.h>

// HMM scaled forward, MFMA + telescoped normalization.
//   BATCH=128, T=8192, N_STATES=128, EMIT=64
// 1) decode_onehot: 256 MiB one-hot -> obsG[bg][t][16] bytes (1 MiB)
// 2) zero_ll: zero the loglik region of d_out
// 3) hmm_scan: one wave per (batch-group of 16, time-chunk of 32 + 16 warmup).
//    Chain runs UNNORMALIZED: B-table pre-scaled by 64 (exact pow2) keeps
//    magnitudes centered; bf16/fp32 exponent range absorbs the drift.
//    Sum log Z telescopes: chunk ll = log(S_end) - log(S_pre) - 32*ln(64),
//    so the per-step shfl-reduce / log / rcp / normalize are GONE.
//    Per step: 4x ds_read_b128 (alpha^T) -> 32x mfma 16x16x32_bf16
//    (A^T static in 128 VGPRs) -> 8x ds_read_b64 (64*B emission, bf16)
//    -> 32 muls -> v_perm pack -> 8x ds_write_b64.

#define BATCH 128
#define TLEN 8192
#define NS 128
#define EMIT 64
#define NCHUNK 256
#define CLEN (TLEN / NCHUNK)   // 32
#define WARM 16
#define BG 8                   // batch groups of 16
#define ASTRIDE 136            // alphaT row stride (bf16 elems; 272 B, 16B-aligned)
#define BSTR 132               // B-table row stride (bf16 elems)
#define LN64 4.158883083359672f

typedef __attribute__((ext_vector_type(8))) short short8;
typedef __attribute__((ext_vector_type(4))) float floatx4;
typedef __attribute__((ext_vector_type(4))) unsigned int uintx4;

__device__ __forceinline__ unsigned f2bf(float f) {
    return (__float_as_uint(f) + 0x8000u) >> 16;   // round-half-up to bf16
}

__global__ __launch_bounds__(256) void decode_onehot(
        const float4* __restrict__ x, unsigned char* __restrict__ obsG) {
    int i = blockIdx.x * 256 + threadIdx.x;   // BATCH*TLEN*16 float4s
    float4 v = x[i];
    float s = v.x + v.y + v.z + v.w;
    if (s > 0.5f) {
        int e = (v.y > 0.5f) ? 1 : (v.z > 0.5f) ? 2 : (v.w > 0.5f) ? 3 : 0;
        int elem = (i << 2) + e;
        int row = elem >> 6;              // b*TLEN + t
        int col = elem & 63;              // emission symbol
        int b = row >> 13;                // row / TLEN
        int t = row & (TLEN - 1);
        obsG[(b >> 4) * (TLEN * 16) + t * 16 + (b & 15)] = (unsigned char)col;
    }
}

__global__ void zero_ll(float* __restrict__ out_ll) {
    out_ll[threadIdx.x] = 0.f;
}

__global__ __launch_bounds__(64) void hmm_scan(
        const float* __restrict__ Amat,
        const float* __restrict__ Bmat,
        const float* __restrict__ Ivec,
        const unsigned char* __restrict__ obsG,
        float* __restrict__ out_alpha,    // [BATCH][NS]
        float* __restrict__ out_ll)       // [BATCH]
{
    __shared__ unsigned short Bl[EMIT * BSTR];        // 16896 B: bf16(64*B)
    __shared__ unsigned short aT[16 * ASTRIDE];       // 4352 B: alpha^T (bf16)
    __shared__ unsigned char obs_l[(CLEN + WARM) * 16];

    const int lane = threadIdx.x;
    const int n = lane & 15;              // batch within group
    const int q = lane >> 4;              // quad
    const int bg = blockIdx.x >> 8;       // / NCHUNK
    const int c = blockIdx.x & (NCHUNK - 1);
    const bool first = (c == 0);
    const bool lastc = (c == NCHUNK - 1);
    const int steps = first ? CLEN : (CLEN + WARM);
    const int t0 = first ? 0 : c * CLEN - WARM;

    // stage B scaled by 64 (exact pow2) as bf16, padded stride
    for (int i = lane; i < EMIT * NS; i += 64) {
        int e = i >> 7, col = i & (NS - 1);
        Bl[e * BSTR + col] = (unsigned short)f2bf(64.0f * Bmat[i]);
    }
    // stage obs bytes for this chunk
    {
        const unsigned* src = (const unsigned*)(obsG + bg * (TLEN * 16) + t0 * 16);
        unsigned* dst = (unsigned*)obs_l;
        for (int i = lane; i < steps * 4; i += 64) dst[i] = src[i];
    }
    // warmup init: uniform alpha (bf16(1/128) = 0x3C00); direction-only, scale free
    if (!first) {
        unsigned* dst = (unsigned*)aT;
        for (int i = lane; i < 16 * ASTRIDE / 2; i += 64) dst[i] = 0x3C003C00u;
    }
    // A^T fragments: af[mt][kf], lane layout A_op[m=lane&15][k=8q+j], A_op[m][k]=A[k][m]
    short8 af[8][4];
    #pragma unroll
    for (int mt = 0; mt < 8; ++mt)
        #pragma unroll
        for (int kf = 0; kf < 4; ++kf) {
            short8 v;
            #pragma unroll
            for (int j = 0; j < 8; ++j)
                v[j] = (short)f2bf(Amat[(32 * kf + 8 * q + j) * NS + 16 * mt + n]);
            af[mt][kf] = v;
        }
    __syncthreads();

    float s_pre = 1.0f;     // S-bar at warmup boundary (chunk0: 1 by convention)
    float s_penult = 1.0f;  // S-bar at second-to-last step (last chunk only)
    float s_end = 1.0f;

    for (int it = 0; it < steps; ++it) {
        floatx4 acc[8];
        if (first && it == 0) {
            // t==0: alpha0-bar = (64B)[o] * I  (exact init, R := I)
            #pragma unroll
            for (int mt = 0; mt < 8; ++mt)
                acc[mt] = *(const floatx4*)(Ivec + 16 * mt + 4 * q);
        } else {
            short8 bf[4];
            #pragma unroll
            for (int kf = 0; kf < 4; ++kf) {
                uintx4 u = *(const uintx4*)(aT + n * ASTRIDE + 32 * kf + 8 * q);
                bf[kf] = __builtin_bit_cast(short8, u);
            }
            #pragma unroll
            for (int mt = 0; mt < 8; ++mt) {
                floatx4 a = {0.f, 0.f, 0.f, 0.f};
                #pragma unroll
                for (int kf = 0; kf < 4; ++kf)
                    a = __builtin_amdgcn_mfma_f32_16x16x32_bf16(af[mt][kf], bf[kf], a, 0, 0, 0);
                acc[mt] = a;
            }
        }

        // emission multiply (table already holds 64*B)
        int o = obs_l[it * 16 + n];
        #pragma unroll
        for (int mt = 0; mt < 8; ++mt) {
            const unsigned* ep = (const unsigned*)(Bl + o * BSTR + 16 * mt + 4 * q);
            unsigned d0 = ep[0], d1 = ep[1];
            acc[mt].x *= __uint_as_float(d0 << 16);
            acc[mt].y *= __uint_as_float(d0 & 0xFFFF0000u);
            acc[mt].z *= __uint_as_float(d1 << 16);
            acc[mt].w *= __uint_as_float(d1 & 0xFFFF0000u);
        }

        // rare per-chunk reductions (wave-uniform branch)
        bool need_red = (it == steps - 1) || (!first && it == WARM - 1) ||
                        (lastc && it == steps - 2);
        if (need_red) {
            float zz = 0.f;
            #pragma unroll
            for (int mt = 0; mt < 8; ++mt)
                zz += (acc[mt].x + acc[mt].y) + (acc[mt].z + acc[mt].w);
            zz += __shfl_xor(zz, 16, 64);
            zz += __shfl_xor(zz, 32, 64);    // full S-bar per batch, all q-lanes
            if (it == steps - 1) s_end = zz;
            else if (lastc && it == steps - 2) s_penult = zz;
            else s_pre = zz;
        }

        if (lastc && it == steps - 1) {
            // alpha_f = alpha-bar_{T-1} / (64 * S-bar_{T-2})
            float inv = 1.0f / (64.0f * s_penult);
            #pragma unroll
            for (int mt = 0; mt < 8; ++mt) {
                floatx4 o4;
                o4.x = acc[mt].x * inv; o4.y = acc[mt].y * inv;
                o4.z = acc[mt].z * inv; o4.w = acc[mt].w * inv;
                *(floatx4*)(out_alpha + (bg * 16 + n) * NS + 16 * mt + 4 * q) = o4;
            }
        }

        // pack to bf16 (round-half-up via +0x8000, merge with v_perm) and store
        #pragma unroll
        for (int mt = 0; mt < 8; ++mt) {
            unsigned u0 = __float_as_uint(acc[mt].x) + 0x8000u;
            unsigned u1 = __float_as_uint(acc[mt].y) + 0x8000u;
            unsigned u2 = __float_as_uint(acc[mt].z) + 0x8000u;
            unsigned u3 = __float_as_uint(acc[mt].w) + 0x8000u;
            unsigned lo = __builtin_amdgcn_perm(u1, u0, 0x07060302u);
            unsigned hi = __builtin_amdgcn_perm(u3, u2, 0x07060302u);
            unsigned* wp = (unsigned*)(aT + n * ASTRIDE + 16 * mt + 4 * q);
            wp[0] = lo; wp[1] = hi;
        }
        __syncthreads();   // single-wave WG: orders aT RAW
    }

    // chunk ll partial: telescoped  log(S_end) - log(S_pre) - CLEN*ln(64)
    if (q == 0) {
        float ll = __logf(s_end) - __logf(s_pre) - (float)CLEN * LN64;
        atomicAdd(&out_ll[bg * 16 + n], ll);
    }
}

extern "C" void kernel_launch(void* const* d_in, const int* in_sizes, int n_in,
                              void* d_out, int out_size, void* d_ws, size_t ws_size,
                              hipStream_t stream) {
    const float* x = (const float*)d_in[0];   // [B, T, EMIT] one-hot fp32
    const float* I = (const float*)d_in[1];   // [NS]
    const float* A = (const float*)d_in[2];   // [NS, NS]
    const float* B = (const float*)d_in[3];   // [EMIT, NS]
    float* out = (float*)d_out;               // alpha_f [B*NS] ++ loglik [B]

    unsigned char* obsG = (unsigned char*)d_ws;   // [BG][TLEN][16] bytes = 1 MiB

    decode_onehot<<<(BATCH * TLEN * 16) / 256, 256, 0, stream>>>(
        (const float4*)x, obsG);
    zero_ll<<<1, BATCH, 0, stream>>>(out + BATCH * NS);
    hmm_scan<<<BG * NCHUNK, 64, 0, stream>>>(A, B, I, obsG, out, out + BATCH * NS);
}

// Round 5
// 389.253 us; speedup vs baseline: 3.8401x; 1.1419x over previous
//
#include <hip/hip_runtime.h>

// HMM scaled forward, register-resident MFMA recurrence.
//   BATCH=128, T=8192, N_STATES=128, EMIT=64
// Key trick: permute A's K-ordering so the MFMA D-output (packed to bf16)
// IS the next step's B-fragment — alpha never leaves registers. Per step:
// 32x mfma_f32_16x16x32_bf16 -> 8x ds_read_b64 (emission) -> 32 mul ->
// 16 v_perm pack. No LDS round-trip, no barrier in the loop.
// Normalization telescoped (B-table pre-scaled by 64): only 2-3 shfl
// reductions per chunk. Chunks of 32 with 8 warmup steps from uniform.

#define BATCH 128
#define TLEN 8192
#define NS 128
#define EMIT 64
#define NCHUNK 256
#define CLEN (TLEN / NCHUNK)   // 32
#define WARM 8
#define BG 8                   // batch groups of 16
#define BSTR 132               // B-table row stride (bf16 elems)
#define LN64 4.158883083359672f

typedef __attribute__((ext_vector_type(8))) short short8;
typedef __attribute__((ext_vector_type(4))) float floatx4;
typedef __attribute__((ext_vector_type(4))) unsigned int uintx4;

__device__ __forceinline__ unsigned f2bf(float f) {
    return (__float_as_uint(f) + 0x8000u) >> 16;   // round-half-up to bf16
}

// decode 256 MiB one-hot -> obsG[bg][n][t] bytes (1 MiB); also zeroes out_ll
__global__ __launch_bounds__(256) void decode_onehot(
        const floatx4* __restrict__ x, unsigned char* __restrict__ obsG,
        float* __restrict__ out_ll) {
    if (blockIdx.x == 0 && threadIdx.x < BATCH) out_ll[threadIdx.x] = 0.f;
    int base = blockIdx.x * 512 + threadIdx.x;
    #pragma unroll
    for (int h = 0; h < 2; ++h) {
        int i = base + h * 256;                    // BATCH*TLEN*16 float4s
        floatx4 v = __builtin_nontemporal_load(&x[i]);
        float s = v.x + v.y + v.z + v.w;
        if (s > 0.5f) {
            int e = (v.y > 0.5f) ? 1 : (v.z > 0.5f) ? 2 : (v.w > 0.5f) ? 3 : 0;
            int elem = (i << 2) + e;
            int row = elem >> 6;                   // b*TLEN + t
            int col = elem & 63;                   // emission symbol
            int b = row >> 13;
            int t = row & (TLEN - 1);
            obsG[(b >> 4) * (16 * TLEN) + (b & 15) * TLEN + t] = (unsigned char)col;
        }
    }
}

__global__ __launch_bounds__(64) void hmm_scan(
        const float* __restrict__ Amat,
        const float* __restrict__ Bmat,
        const float* __restrict__ Ivec,
        const unsigned char* __restrict__ obsG,
        float* __restrict__ out_alpha,    // [BATCH][NS]
        float* __restrict__ out_ll)       // [BATCH]
{
    __shared__ unsigned short Bl[EMIT * BSTR];    // 16896 B: bf16(64*B)

    const int lane = threadIdx.x;
    const int n = lane & 15;              // batch within group (D col)
    const int q = lane >> 4;              // quad
    const int bg = blockIdx.x >> 8;       // / NCHUNK
    const int c = blockIdx.x & (NCHUNK - 1);
    const bool first = (c == 0);
    const bool lastc = (c == NCHUNK - 1);
    const int steps = first ? CLEN : (CLEN + WARM);
    const int t0 = first ? 0 : c * CLEN - WARM;

    // stage B scaled by 64 (exact pow2) as bf16, padded stride
    for (int i = lane; i < EMIT * NS; i += 64) {
        int e = i >> 7, col = i & (NS - 1);
        Bl[e * BSTR + col] = (unsigned short)f2bf(64.0f * Bmat[i]);
    }

    // this lane's obs bytes -> 10 dwords in registers (obsG row is batch n)
    const unsigned char* orow = obsG + bg * (16 * TLEN) + n * TLEN;
    unsigned ow[10];
    if (first) {                          // t0==0, 32 bytes, 16B aligned
        uintx4 a = *(const uintx4*)(orow);
        uintx4 b = *(const uintx4*)(orow + 16);
        ow[0] = a.x; ow[1] = a.y; ow[2] = a.z; ow[3] = a.w;
        ow[4] = b.x; ow[5] = b.y; ow[6] = b.z; ow[7] = b.w;
        ow[8] = 0; ow[9] = 0;
    } else {                              // t0 = 32c-8: 8B then 16B aligned
        uint2 a = *(const uint2*)(orow + t0);
        uintx4 b = *(const uintx4*)(orow + t0 + 8);
        uintx4 d = *(const uintx4*)(orow + t0 + 24);
        ow[0] = a.x; ow[1] = a.y;
        ow[2] = b.x; ow[3] = b.y; ow[4] = b.z; ow[5] = b.w;
        ow[6] = d.x; ow[7] = d.y; ow[8] = d.z; ow[9] = d.w;
    }

    // A fragments with permuted K-order so packed D == next B-frag.
    // position u = 32kf + 8q + j  ->  state  32(u>>5)+16((u>>2)&1)+4((u>>3)&3)+(u&3)
    short8 af[8][4];
    #pragma unroll
    for (int mt = 0; mt < 8; ++mt)
        #pragma unroll
        for (int kf = 0; kf < 4; ++kf) {
            short8 v;
            #pragma unroll
            for (int j = 0; j < 8; ++j) {
                int u = 32 * kf + 8 * q + j;
                int sk = 32 * (u >> 5) + 16 * ((u >> 2) & 1)
                       + 4 * ((u >> 3) & 3) + (u & 3);
                v[j] = (short)f2bf(Amat[sk * NS + 16 * mt + n]);
            }
            af[mt][kf] = v;
        }
    __syncthreads();   // Bl ready

    // loop-carried packed alpha (bf16 pairs); init uniform for warmup
    unsigned pk[16];
    #pragma unroll
    for (int i = 0; i < 16; ++i) pk[i] = 0x3C003C00u;   // bf16(1/128) x2

    float s_pre = 1.0f, s_penult = 1.0f, s_end = 1.0f;

    for (int it = 0; it < steps; ++it) {
        floatx4 acc[8];
        if (first && it == 0) {
            // t==0: R := I (exact init), alpha0 = 64B[o] * I
            #pragma unroll
            for (int mt = 0; mt < 8; ++mt)
                acc[mt] = *(const floatx4*)(Ivec + 16 * mt + 4 * q);
        } else {
            short8 bf[4];
            #pragma unroll
            for (int kf = 0; kf < 4; ++kf) {
                uintx4 u4 = {pk[4 * kf], pk[4 * kf + 1], pk[4 * kf + 2], pk[4 * kf + 3]};
                bf[kf] = __builtin_bit_cast(short8, u4);
            }
            #pragma unroll
            for (int mt = 0; mt < 8; ++mt) {
                floatx4 a = {0.f, 0.f, 0.f, 0.f};
                #pragma unroll
                for (int kf = 0; kf < 4; ++kf)
                    a = __builtin_amdgcn_mfma_f32_16x16x32_bf16(af[mt][kf], bf[kf], a, 0, 0, 0);
                acc[mt] = a;
            }
        }

        // emission multiply (table holds 64*B)
        int o = (ow[it >> 2] >> ((it & 3) * 8)) & 0xFF;
        int eb = o * BSTR;
        #pragma unroll
        for (int mt = 0; mt < 8; ++mt) {
            const unsigned* ep = (const unsigned*)(Bl + eb + 16 * mt + 4 * q);
            unsigned d0 = ep[0], d1 = ep[1];
            acc[mt].x *= __uint_as_float(d0 << 16);
            acc[mt].y *= __uint_as_float(d0 & 0xFFFF0000u);
            acc[mt].z *= __uint_as_float(d1 << 16);
            acc[mt].w *= __uint_as_float(d1 & 0xFFFF0000u);
        }

        // rare per-chunk reductions (wave-uniform branch)
        bool need_red = (it == steps - 1) || (!first && it == WARM - 1) ||
                        (lastc && it == steps - 2);
        if (need_red) {
            float zz = 0.f;
            #pragma unroll
            for (int mt = 0; mt < 8; ++mt)
                zz += (acc[mt].x + acc[mt].y) + (acc[mt].z + acc[mt].w);
            zz += __shfl_xor(zz, 16, 64);
            zz += __shfl_xor(zz, 32, 64);      // S-bar per batch, all q-lanes
            if (it == steps - 1) s_end = zz;
            else if (lastc && it == steps - 2) s_penult = zz;
            else s_pre = zz;
        }

        if (lastc && it == steps - 1) {
            // alpha_f = alpha-bar_{T-1} / (64 * S-bar_{T-2})
            float inv = 1.0f / (64.0f * s_penult);
            #pragma unroll
            for (int mt = 0; mt < 8; ++mt) {
                floatx4 o4;
                o4.x = acc[mt].x * inv; o4.y = acc[mt].y * inv;
                o4.z = acc[mt].z * inv; o4.w = acc[mt].w * inv;
                *(floatx4*)(out_alpha + (bg * 16 + n) * NS + 16 * mt + 4 * q) = o4;
            }
        }

        // pack to bf16 pairs: directly forms next step's B-fragments
        #pragma unroll
        for (int mt = 0; mt < 8; ++mt) {
            unsigned u0 = __float_as_uint(acc[mt].x) + 0x8000u;
            unsigned u1 = __float_as_uint(acc[mt].y) + 0x8000u;
            unsigned u2 = __float_as_uint(acc[mt].z) + 0x8000u;
            unsigned u3 = __float_as_uint(acc[mt].w) + 0x8000u;
            pk[2 * mt]     = __builtin_amdgcn_perm(u1, u0, 0x07060302u);
            pk[2 * mt + 1] = __builtin_amdgcn_perm(u3, u2, 0x07060302u);
        }
    }

    // chunk ll partial: telescoped  log(S_end) - log(S_pre) - CLEN*ln(64)
    if (q == 0) {
        float ll = __logf(s_end) - __logf(s_pre) - (float)CLEN * LN64;
        atomicAdd(&out_ll[bg * 16 + n], ll);
    }
}

extern "C" void kernel_launch(void* const* d_in, const int* in_sizes, int n_in,
                              void* d_out, int out_size, void* d_ws, size_t ws_size,
                              hipStream_t stream) {
    const float* x = (const float*)d_in[0];   // [B, T, EMIT] one-hot fp32
    const float* I = (const float*)d_in[1];   // [NS]
    const float* A = (const float*)d_in[2];   // [NS, NS]
    const float* B = (const float*)d_in[3];   // [EMIT, NS]
    float* out = (float*)d_out;               // alpha_f [B*NS] ++ loglik [B]

    unsigned char* obsG = (unsigned char*)d_ws;   // [BG][16][TLEN] bytes = 1 MiB

    decode_onehot<<<(BATCH * TLEN * 16) / 512, 256, 0, stream>>>(
        (const floatx4*)x, obsG, out + BATCH * NS);
    hmm_scan<<<BG * NCHUNK, 64, 0, stream>>>(A, B, I, obsG, out, out + BATCH * NS);
}